// Round 5
// baseline (17078.418 us; speedup 1.0000x reference)
//
#include <hip/hip_runtime.h>
#include <math.h>

// Problem constants (fixed by setup_inputs)
constexpr int U      = 128;   // UNITS
constexpr int G4     = 512;   // 4*U gate width
constexpr int NCls   = 10;    // classes
constexpr int TSTEPS = 1000;
constexpr int BATCH  = 256;
constexpr int NB     = 4;     // batch elements per block

// ---------------------------------------------------------------------------
// Round-4 baseline (9.4 us/step) was L2-BW-floored: every block re-reads all
// 768 KB of Wh0/Wx1/Wh1 from L2 each step -> 25 GB per XCD over the sequence,
// ~5.9 us/step at 4.3 TB/s per-XCD L2. This version amortizes each weight
// read over NB=4 batch elements (grid 64, one block = 4 sequences):
//   - matvec phases: thread j owns column j; one weight load feeds 4 FMAs
//     (one per element) -> L2 bytes per element / 4
//   - gate/LN phases: all 8 waves active (thread group e = element e),
//     previously only 2 of 8 waves worked
//   - FC/softmax: waves 0..3, one element each, overlapping next matvec0
// Memory pattern per load is IDENTICAL to round 4 (per-use L2 loads, no
// long-range prefetch - rounds 1-3 proved that pattern catastrophic).
// All per-element register arrays use compile-time indices only (unrolled);
// runtime element id (j>>7) touches LDS / select-chains only -> no scratch.
// VGPR demand ~100 < 128 cap.
// ---------------------------------------------------------------------------

__device__ __forceinline__ float sigm(float x) {
    return 1.0f / (1.0f + __expf(-x));
}

// k = time_gate(t, tau, s); floor-mod semantics matching jnp.mod
__device__ __forceinline__ float tgate(float t, float tau, float s) {
    float r = fmodf(t - s, tau);
    if (r < 0.0f) r += tau;
    const float phi = r / tau;
    return (phi < 0.025f) ? 40.0f * phi
         : (phi < 0.05f)  ? 2.0f - 40.0f * phi
         : 0.001f * phi;
}

__global__ __launch_bounds__(512, 1) void plstm_fused(
    const float* __restrict__ inputs,  // [B,T,3]
    const float* __restrict__ times,   // [B,T]
    const float* __restrict__ Wx0,     // [3,512]
    const float* __restrict__ Wh0,     // [128,512]
    const float* __restrict__ b0,      // [512]
    const float* __restrict__ tau0,    // [128]
    const float* __restrict__ s0,      // [128]
    const float* __restrict__ Wx1,     // [128,512]
    const float* __restrict__ Wh1,     // [128,512]
    const float* __restrict__ b1,      // [512]
    const float* __restrict__ tau1,    // [128]
    const float* __restrict__ s1,      // [128]
    const float* __restrict__ gamma_,  // [128]
    const float* __restrict__ beta_,   // [128]
    const float* __restrict__ Wfc,     // [128,10]
    const float* __restrict__ bfc,     // [10]
    float* __restrict__ out)           // [B,T,10]
{
    const int j  = threadIdx.x;          // 0..511 (column id in matvec phases)
    const int b4 = blockIdx.x * NB;      // first batch element of this block
    const int jj = j & 127;              // unit id in gate phases
    const int eg = j >> 7;               // element id in gate phases (runtime!)

    __shared__ __align__(16) float zs4[NB][G4];    // 8 KB
    __shared__ __align__(16) float h0s4[NB][U];    // 2 KB
    __shared__ __align__(16) float gh0s4[NB][U];   // gamma[u]*h0[u]
    __shared__ __align__(16) float h1s4[NB][U];
    __shared__ __align__(16) float wfcs[U * 11];   // stride 11: no bank aliasing
    __shared__ float bfcs[NCls];
    __shared__ float red[16];                      // per-wave {sum, sq}
    __shared__ float gms[U], bts[U];               // gamma, beta staged

    // ---- prologue ----
    if (j < U) { gms[j] = gamma_[j]; bts[j] = beta_[j]; }
    for (int i = j; i < U * NCls; i += 512) {
        const int u = i / NCls, c = i - u * NCls;
        wfcs[u * 11 + c] = Wfc[i];
    }
    if (j < NCls) bfcs[j] = bfc[j];
    h0s4[eg][jj] = 0.0f; gh0s4[eg][jj] = 0.0f; h1s4[eg][jj] = 0.0f;
    __syncthreads();

    // ---- LayerNorm fold constants: P[j] = sum_u beta[u]*Wx1[u][j],
    //      Q[j] = sum_u gamma[u]*Wx1[u][j] ----
    float Pj = 0.0f, Qj = 0.0f;
    #pragma unroll 8
    for (int u = 0; u < U; ++u) {
        const float w = Wx1[u * G4 + j];
        Qj += gms[u] * w;
        Pj += bts[u] * w;
    }

    // ---- per-thread persistent parameters ----
    const float bj0  = b0[j];
    const float bj1  = b1[j];
    const float wx00 = Wx0[j];
    const float wx01 = Wx0[G4 + j];
    const float wx02 = Wx0[2 * G4 + j];
    const float tau0r = tau0[jj], s0r = s0[jj];
    const float tau1r = tau1[jj], s1r = s1[jj];
    const float gr    = gms[jj];
    float c0r = 0.f, c1r = 0.f, h0r = 0.f, h1r = 0.f;   // state of (eg, jj)

    // Per-thread column bases and per-element sequence pointers
    const float* __restrict__ wh0p = Wh0 + j;
    const float* __restrict__ wx1p = Wx1 + j;
    const float* __restrict__ wh1p = Wh1 + j;
    const float* xp[NB];
    const float* tpp[NB];
    #pragma unroll
    for (int e = 0; e < NB; ++e) {
        xp[e]  = inputs + (size_t)(b4 + e) * TSTEPS * 3;
        tpp[e] = times  + (size_t)(b4 + e) * TSTEPS;
    }

    __syncthreads();

    for (int t = 0; t < TSTEPS; ++t) {
        // ---- per-element x, t (uniform scalar loads; compile-time e only) ----
        float xv0[NB], xv1[NB], xv2[NB], tv[NB];
        #pragma unroll
        for (int e = 0; e < NB; ++e) {
            xv0[e] = xp[e][t * 3 + 0];
            xv1[e] = xp[e][t * 3 + 1];
            xv2[e] = xp[e][t * 3 + 2];
            tv[e]  = tpp[e][t];
        }
        // runtime-eg select chain (registers, no scratch)
        float tve = tv[0];
        #pragma unroll
        for (int e = 1; e < NB; ++e) if (eg == e) tve = tv[e];

        // ---- phase A: matvec0; 1 weight load -> NB FMAs ----
        float acA[NB], acB[NB];
        #pragma unroll
        for (int e = 0; e < NB; ++e) {
            acA[e] = bj0 + xv0[e] * wx00 + xv1[e] * wx01;
            acB[e] = xv2[e] * wx02;
        }
        #pragma unroll 4
        for (int u = 0; u < U; u += 4) {
            const float w0 = wh0p[(u + 0) * G4];
            const float w1 = wh0p[(u + 1) * G4];
            const float w2 = wh0p[(u + 2) * G4];
            const float w3 = wh0p[(u + 3) * G4];
            #pragma unroll
            for (int e = 0; e < NB; ++e) {
                const float4 h4 = *reinterpret_cast<const float4*>(&h0s4[e][u]);
                acA[e] += h4.x * w0;
                acB[e] += h4.y * w1;
                acA[e] += h4.z * w2;
                acB[e] += h4.w * w3;
            }
        }
        #pragma unroll
        for (int e = 0; e < NB; ++e) zs4[e][j] = acA[e] + acB[e];
        __syncthreads();                                   // B1

        // ---- phase B: gates0 + LN partials (ALL waves; group eg) ----
        {
            const float ig = sigm(zs4[eg][jj]);
            const float fg = sigm(zs4[eg][jj + 128]);
            const float gg = tanhf(zs4[eg][jj + 256]);
            const float og = sigm(zs4[eg][jj + 384]);
            const float ch = fg * c0r + ig * gg;
            const float hh = og * tanhf(ch);
            const float k  = tgate(tve, tau0r, s0r);
            const float hn = k * hh + (1.0f - k) * h0r;
            c0r = k * ch + (1.0f - k) * c0r;
            h0r = hn;
            h0s4[eg][jj]  = hn;
            gh0s4[eg][jj] = gr * hn;
            float ssum = hn, qsum = hn * hn;               // one-pass variance
            #pragma unroll
            for (int off = 1; off < 64; off <<= 1) {
                ssum += __shfl_xor(ssum, off);
                qsum += __shfl_xor(qsum, off);
            }
            if ((j & 63) == 0) {
                red[(j >> 6) * 2]     = ssum;              // wave w -> red[2w..]
                red[(j >> 6) * 2 + 1] = qsum;
            }
        }
        __syncthreads();                                   // B2

        // ---- phase C: matvec1 with LN folded; 1 load -> NB FMAs ----
        float ax[NB] = {0.f, 0.f, 0.f, 0.f};
        float ah[NB] = {0.f, 0.f, 0.f, 0.f};
        #pragma unroll 2
        for (int u = 0; u < U; u += 4) {
            const float wxa = wx1p[(u + 0) * G4];
            const float wxb = wx1p[(u + 1) * G4];
            const float wxc = wx1p[(u + 2) * G4];
            const float wxd = wx1p[(u + 3) * G4];
            const float wha = wh1p[(u + 0) * G4];
            const float whb = wh1p[(u + 1) * G4];
            const float whc = wh1p[(u + 2) * G4];
            const float whd = wh1p[(u + 3) * G4];
            #pragma unroll
            for (int e = 0; e < NB; ++e) {
                const float4 g4 = *reinterpret_cast<const float4*>(&gh0s4[e][u]);
                const float4 h4 = *reinterpret_cast<const float4*>(&h1s4[e][u]);
                ax[e] += g4.x * wxa;  ah[e] += h4.x * wha;
                ax[e] += g4.y * wxb;  ah[e] += h4.y * whb;
                ax[e] += g4.z * wxc;  ah[e] += h4.z * whc;
                ax[e] += g4.w * wxd;  ah[e] += h4.w * whd;
            }
        }
        #pragma unroll
        for (int e = 0; e < NB; ++e) {
            // element e's LN stats: waves 2e (units 0..63) and 2e+1 (64..127)
            const float ss   = red[4 * e]     + red[4 * e + 2];
            const float qq   = red[4 * e + 1] + red[4 * e + 3];
            const float mu   = ss * (1.0f / 128.0f);
            const float rstd = rsqrtf(qq * (1.0f / 128.0f) - mu * mu + 1e-3f);
            // z1 = b1 + P + rstd*Swx - mu*rstd*Q + Swh   (exact LN fold)
            zs4[e][j] = bj1 + Pj + rstd * ax[e] - (mu * rstd) * Qj + ah[e];
        }
        __syncthreads();                                   // B3

        // ---- phase D: gates1 (ALL waves; group eg) ----
        {
            const float ig = sigm(zs4[eg][jj]);
            const float fg = sigm(zs4[eg][jj + 128]);
            const float gg = tanhf(zs4[eg][jj + 256]);
            const float og = sigm(zs4[eg][jj + 384]);
            const float ch = fg * c1r + ig * gg;
            const float hh = og * tanhf(ch);
            const float k  = tgate(tve, tau1r, s1r);
            const float hn = k * hh + (1.0f - k) * h1r;
            c1r = k * ch + (1.0f - k) * c1r;
            h1r = hn;
            h1s4[eg][jj] = hn;
        }
        __syncthreads();                                   // B4

        // ---- phase E: FC + softmax (waves 0..3, one element each);
        //      waves 4..7 roll straight into step t+1's matvec0 ----
        if (j < 64 * NB) {
            const int e    = j >> 6;       // element (uniform per wave)
            const int lane = j & 63;
            const float a  = h1s4[e][lane];
            const float bv = h1s4[e][lane + 64];
            float p[NCls];
            #pragma unroll
            for (int c = 0; c < NCls; ++c)
                p[c] = a * wfcs[lane * 11 + c] + bv * wfcs[(lane + 64) * 11 + c];
            #pragma unroll
            for (int off = 1; off < 64; off <<= 1) {
                #pragma unroll
                for (int c = 0; c < NCls; ++c) p[c] += __shfl_xor(p[c], off);
            }
            float m = -1e30f;
            #pragma unroll
            for (int c = 0; c < NCls; ++c) { p[c] += bfcs[c]; m = fmaxf(m, p[c]); }
            float ssum = 0.0f;
            #pragma unroll
            for (int c = 0; c < NCls; ++c) { p[c] = __expf(p[c] - m); ssum += p[c]; }
            const float inv = 1.0f / ssum;
            float pv = p[0];               // static-index select (no scratch)
            #pragma unroll
            for (int c = 1; c < NCls; ++c) if (lane == c) pv = p[c];
            if (lane < NCls) {
                float* ope = out + (size_t)(b4 + e) * TSTEPS * NCls;  // arithmetic, not array
                ope[t * NCls + lane] = pv * inv;
            }
        }
        // No trailing barrier: phase A(t+1) touches zs4 / h0s4 / weights only,
        // disjoint from phase E's h1s4/wfcs reads; B1 fences the next hazard.
    }
}

extern "C" void kernel_launch(void* const* d_in, const int* in_sizes, int n_in,
                              void* d_out, int out_size, void* d_ws, size_t ws_size,
                              hipStream_t stream) {
    const float* inputs = (const float*)d_in[0];
    const float* times  = (const float*)d_in[1];
    const float* Wx0    = (const float*)d_in[2];
    const float* Wh0    = (const float*)d_in[3];
    const float* b0     = (const float*)d_in[4];
    const float* tau0   = (const float*)d_in[5];
    const float* s0     = (const float*)d_in[6];
    const float* Wx1    = (const float*)d_in[7];
    const float* Wh1    = (const float*)d_in[8];
    const float* b1     = (const float*)d_in[9];
    const float* tau1   = (const float*)d_in[10];
    const float* s1     = (const float*)d_in[11];
    const float* gamma_ = (const float*)d_in[12];
    const float* beta_  = (const float*)d_in[13];
    const float* Wfc    = (const float*)d_in[14];
    const float* bfc    = (const float*)d_in[15];
    float* out = (float*)d_out;

    dim3 grid(BATCH / NB);
    dim3 block(512);
    hipLaunchKernelGGL(plstm_fused, grid, block, 0, stream,
                       inputs, times, Wx0, Wh0, b0, tau0, s0,
                       Wx1, Wh1, b1, tau1, s1, gamma_, beta_, Wfc, bfc, out);
}

// Round 6
// 7948.050 us; speedup vs baseline: 2.1488x; 2.1488x over previous
//
#include <hip/hip_runtime.h>
#include <math.h>

// Problem constants (fixed by setup_inputs)
constexpr int U      = 128;   // UNITS
constexpr int G4     = 512;   // 4*U gate width
constexpr int NCls   = 10;    // classes
constexpr int TSTEPS = 1000;
constexpr int BATCH  = 256;

// ---------------------------------------------------------------------------
// Evidence so far:
//  r0: naive per-use loads, 512 thr, 6 barriers          15.7 ms
//  r1-r3: long-range register streaming                  29-30 ms (NEVER again)
//  r4: per-use loads + 4 accs + LN-fold + 4 barriers      8.57 ms
//  r5: NB=4 batching, grid 64                            17.1 ms (idles 192 CUs;
//      per-CU L1-port bytes unchanged -> no wall win)
// Bottleneck model (r4/r5 counters): per-CU L1/TA port. Each CU must stream
// the weight working set every step (~64 B/cyc). r4: 768 KB -> ~5.1 us floor,
// + ~3 us VALU poorly overlapped = 9.4 us measured.
// This version: NB=1, grid=256 (all CUs), per-use loads (proven pattern), and
//  - 1024 threads: thread (h=tid>>9, j=tid&511) owns column j, u-half h.
//    Halves per-thread work, 4 waves/SIMD for latency hiding. Partial z in
//    zp[2][512]; gate phase reads zp[0][c]+zp[1][c] (no extra barrier).
//  - 128 KB LDS cache of Wh0 rows {0..31}u{64..95}, packed [h][u4][j][4] so
//    phase A reads them as ds_read_b128 -> L1-port bytes 768 -> 640 KB/step.
//  - LN folded into matvec1 via per-half P/Q partials (exact, as r4).
// All loads are per-use, in-phase. No cross-barrier streaming.
// ---------------------------------------------------------------------------

__device__ __forceinline__ float sigm(float x) {
    return 1.0f / (1.0f + __expf(-x));
}

// k = time_gate(t, tau, s); floor-mod semantics matching jnp.mod
__device__ __forceinline__ float tgate(float t, float tau, float s) {
    float r = fmodf(t - s, tau);
    if (r < 0.0f) r += tau;
    const float phi = r / tau;
    return (phi < 0.025f) ? 40.0f * phi
         : (phi < 0.05f)  ? 2.0f - 40.0f * phi
         : 0.001f * phi;
}

__global__ __launch_bounds__(1024, 1) void plstm_fused(
    const float* __restrict__ inputs,  // [B,T,3]
    const float* __restrict__ times,   // [B,T]
    const float* __restrict__ Wx0,     // [3,512]
    const float* __restrict__ Wh0,     // [128,512]
    const float* __restrict__ b0,      // [512]
    const float* __restrict__ tau0,    // [128]
    const float* __restrict__ s0,      // [128]
    const float* __restrict__ Wx1,     // [128,512]
    const float* __restrict__ Wh1,     // [128,512]
    const float* __restrict__ b1,      // [512]
    const float* __restrict__ tau1,    // [128]
    const float* __restrict__ s1,      // [128]
    const float* __restrict__ gamma_,  // [128]
    const float* __restrict__ beta_,   // [128]
    const float* __restrict__ Wfc,     // [128,10]
    const float* __restrict__ bfc,     // [10]
    float* __restrict__ out)           // [B,T,10]
{
    const int tid = threadIdx.x;         // 0..1023
    const int h   = tid >> 9;            // u-half (0: u<64, 1: u>=64)
    const int j   = tid & 511;           // column
    const int b   = blockIdx.x;

    // 128 KB packed Wh0 cache: rows {64h + 0..31}, layout [(h*8+u4)*512+j][4]
    __shared__ __align__(16) float wh0c[2 * 8 * 512 * 4];
    __shared__ __align__(16) float zp[2][G4];      // layer-0 partials (4 KB)
    __shared__ __align__(16) float zq[2][G4];      // layer-1 partials (4 KB)
    __shared__ __align__(16) float h0s[U];
    __shared__ __align__(16) float gh0s[U];        // gamma[u]*h0[u]
    __shared__ __align__(16) float h1s[U];
    __shared__ __align__(16) float wfcs[U * 11];   // stride 11: no bank aliasing
    __shared__ float bfcs[NCls];
    __shared__ float red[4];                       // {sum0,sq0,sum1,sq1}
    __shared__ float gms[U], bts[U];               // gamma, beta staged

    // ---- prologue ----
    if (tid < U) { gms[tid] = gamma_[tid]; bts[tid] = beta_[tid];
                   h0s[tid] = 0.f; gh0s[tid] = 0.f; h1s[tid] = 0.f; }
    for (int i = tid; i < U * NCls; i += 1024) {
        const int u = i / NCls, c = i - u * NCls;
        wfcs[u * 11 + c] = Wfc[i];
    }
    if (tid < NCls) bfcs[tid] = bfc[tid];
    // pack Wh0 cached rows: cr = 0..63 -> global row r = 64*(cr/32) + cr%32
    #pragma unroll 4
    for (int it = 0; it < 32; ++it) {
        const int cr = it * 2 + (tid >> 9);                  // 0..63
        const int r  = ((cr >> 5) << 6) + (cr & 31);
        const float v = Wh0[r * G4 + j];                     // coalesced
        const int hh = cr >> 5, u4 = (cr & 31) >> 2, s = cr & 3;
        wh0c[(((hh * 8 + u4) * 512) + j) * 4 + s] = v;
    }
    __syncthreads();

    // ---- LayerNorm fold constants (per-half partials over u in [64h,64h+64)):
    //      P_h[j] = sum beta[u]*Wx1[u][j],  Q_h[j] = sum gamma[u]*Wx1[u][j] ----
    const int ub = h * 64;
    float Pj = 0.0f, Qj = 0.0f;
    #pragma unroll 8
    for (int m = 0; m < 64; ++m) {
        const float w = Wx1[(ub + m) * G4 + j];
        Qj += gms[ub + m] * w;
        Pj += bts[ub + m] * w;
    }

    // ---- per-thread persistent parameters ----
    const float bj0  = b0[j];
    const float bj1  = b1[j];
    const float wx00 = Wx0[j];
    const float wx01 = Wx0[G4 + j];
    const float wx02 = Wx0[2 * G4 + j];
    float tau0r = 0.f, s0r = 0.f, tau1r = 0.f, s1r = 0.f, gr = 0.f;
    if (tid < U) {
        tau0r = tau0[tid]; s0r = s0[tid];
        tau1r = tau1[tid]; s1r = s1[tid];
        gr = gms[tid];
    }
    float c0r = 0.f, c1r = 0.f, h0r = 0.f, h1r = 0.f;   // state of unit tid (<128)

    // Column bases for streamed (per-use) loads
    const float* __restrict__ wh0p = Wh0 + (ub + 32) * G4 + j;  // streamed A rows
    const float* __restrict__ wx1p = Wx1 + ub * G4 + j;
    const float* __restrict__ wh1p = Wh1 + ub * G4 + j;
    const float4* __restrict__ wc4 =
        reinterpret_cast<const float4*>(wh0c) + (h * 8) * 512 + j;
    const float* __restrict__ xp = inputs + (size_t)b * TSTEPS * 3;
    const float* __restrict__ tp = times  + (size_t)b * TSTEPS;
    float*       __restrict__ op = out    + (size_t)b * TSTEPS * NCls;

    float xa0 = xp[0], xa1 = xp[1], xa2 = xp[2], tva = tp[0];

    __syncthreads();

    for (int t = 0; t < TSTEPS; ++t) {
        const float x0 = xa0, x1 = xa1, x2 = xa2, tv = tva;
        const int tn = (t + 1 < TSTEPS) ? t + 1 : t;
        xa0 = xp[tn*3+0]; xa1 = xp[tn*3+1]; xa2 = xp[tn*3+2]; tva = tp[tn];

        // ---- phase A: half-matvec0 (32 LDS-cached rows + 32 streamed rows) ----
        float a0, a1, a2, a3;
        if (h == 0) { a0 = bj0 + x0 * wx00; a1 = x1 * wx01; a2 = x2 * wx02; a3 = 0.f; }
        else        { a0 = 0.f; a1 = 0.f; a2 = 0.f; a3 = 0.f; }
        #pragma unroll
        for (int u4 = 0; u4 < 8; ++u4) {                   // cached rows 64h+4u4+s
            const float4 w4 = wc4[u4 * 512];
            const float4 h4 = *reinterpret_cast<const float4*>(&h0s[ub + 4 * u4]);
            a0 += h4.x * w4.x; a1 += h4.y * w4.y;
            a2 += h4.z * w4.z; a3 += h4.w * w4.w;
        }
        #pragma unroll
        for (int m = 0; m < 32; m += 4) {                  // streamed rows 64h+32+m
            const float w0 = wh0p[(m + 0) * G4];
            const float w1 = wh0p[(m + 1) * G4];
            const float w2 = wh0p[(m + 2) * G4];
            const float w3 = wh0p[(m + 3) * G4];
            const float4 h4 = *reinterpret_cast<const float4*>(&h0s[ub + 32 + m]);
            a0 += h4.x * w0; a1 += h4.y * w1;
            a2 += h4.z * w2; a3 += h4.w * w3;
        }
        zp[h][j] = (a0 + a1) + (a2 + a3);
        __syncthreads();                                   // B1

        // ---- phase B: gates0 + LN partials (threads 0..127) ----
        if (tid < U) {
            const float zi = zp[0][tid]       + zp[1][tid];
            const float zf = zp[0][tid + 128] + zp[1][tid + 128];
            const float zg = zp[0][tid + 256] + zp[1][tid + 256];
            const float zo = zp[0][tid + 384] + zp[1][tid + 384];
            const float ig = sigm(zi);
            const float fg = sigm(zf);
            const float gg = tanhf(zg);
            const float og = sigm(zo);
            const float ch = fg * c0r + ig * gg;
            const float hh = og * tanhf(ch);
            const float k  = tgate(tv, tau0r, s0r);
            const float hn = k * hh + (1.0f - k) * h0r;
            c0r = k * ch + (1.0f - k) * c0r;
            h0r = hn;
            h0s[tid]  = hn;
            gh0s[tid] = gr * hn;
            float ssum = hn, qsum = hn * hn;               // one-pass variance
            #pragma unroll
            for (int off = 1; off < 64; off <<= 1) {
                ssum += __shfl_xor(ssum, off);
                qsum += __shfl_xor(qsum, off);
            }
            if ((tid & 63) == 0) {
                red[(tid >> 6) * 2]     = ssum;
                red[(tid >> 6) * 2 + 1] = qsum;
            }
        }
        __syncthreads();                                   // B2

        // ---- phase C: half-matvec1 with LN folded (streamed, per-use) ----
        const float mu   = (red[0] + red[2]) * (1.0f / 128.0f);
        const float msq  = (red[1] + red[3]) * (1.0f / 128.0f);
        const float rstd = rsqrtf(msq - mu * mu + 1e-3f);

        float ax0 = 0.f, ax1 = 0.f, ax2 = 0.f, ax3 = 0.f;  // partial Swx
        float ah0 = 0.f, ah1 = 0.f, ah2 = 0.f, ah3 = 0.f;  // partial Swh
        #pragma unroll 4
        for (int m = 0; m < 64; m += 4) {
            const float wxa = wx1p[(m + 0) * G4];
            const float wxb = wx1p[(m + 1) * G4];
            const float wxc = wx1p[(m + 2) * G4];
            const float wxd = wx1p[(m + 3) * G4];
            const float wha = wh1p[(m + 0) * G4];
            const float whb = wh1p[(m + 1) * G4];
            const float whc = wh1p[(m + 2) * G4];
            const float whd = wh1p[(m + 3) * G4];
            const float4 g4 = *reinterpret_cast<const float4*>(&gh0s[ub + m]);
            const float4 h4 = *reinterpret_cast<const float4*>(&h1s[ub + m]);
            ax0 += g4.x * wxa;  ah0 += h4.x * wha;
            ax1 += g4.y * wxb;  ah1 += h4.y * whb;
            ax2 += g4.z * wxc;  ah2 += h4.z * whc;
            ax3 += g4.w * wxd;  ah3 += h4.w * whd;
        }
        const float Swx = (ax0 + ax1) + (ax2 + ax3);
        const float Swh = (ah0 + ah1) + (ah2 + ah3);
        // z1_partial = [h==0]*b1 + P_h + rstd*Swx_h - mu*rstd*Q_h + Swh_h
        zq[h][j] = (h == 0 ? bj1 : 0.f) + Pj + rstd * Swx - (mu * rstd) * Qj + Swh;
        __syncthreads();                                   // B3

        // ---- phase D: gates1 (threads 0..127) ----
        if (tid < U) {
            const float zi = zq[0][tid]       + zq[1][tid];
            const float zf = zq[0][tid + 128] + zq[1][tid + 128];
            const float zg = zq[0][tid + 256] + zq[1][tid + 256];
            const float zo = zq[0][tid + 384] + zq[1][tid + 384];
            const float ig = sigm(zi);
            const float fg = sigm(zf);
            const float gg = tanhf(zg);
            const float og = sigm(zo);
            const float ch = fg * c1r + ig * gg;
            const float hh = og * tanhf(ch);
            const float k  = tgate(tv, tau1r, s1r);
            const float hn = k * hh + (1.0f - k) * h1r;
            c1r = k * ch + (1.0f - k) * c1r;
            h1r = hn;
            h1s[tid] = hn;
        }
        __syncthreads();                                   // B4

        // ---- phase E: FC + softmax (wave 0); other waves roll into t+1 ----
        if (tid < 64) {
            const float a  = h1s[tid];
            const float bv = h1s[tid + 64];
            float p[NCls];
            #pragma unroll
            for (int c = 0; c < NCls; ++c)
                p[c] = a * wfcs[tid * 11 + c] + bv * wfcs[(tid + 64) * 11 + c];
            #pragma unroll
            for (int off = 1; off < 64; off <<= 1) {
                #pragma unroll
                for (int c = 0; c < NCls; ++c) p[c] += __shfl_xor(p[c], off);
            }
            float m = -1e30f;
            #pragma unroll
            for (int c = 0; c < NCls; ++c) { p[c] += bfcs[c]; m = fmaxf(m, p[c]); }
            float ssum = 0.0f;
            #pragma unroll
            for (int c = 0; c < NCls; ++c) { p[c] = __expf(p[c] - m); ssum += p[c]; }
            const float inv = 1.0f / ssum;
            float pv = p[0];               // static-index select (no scratch)
            #pragma unroll
            for (int c = 1; c < NCls; ++c) if (tid == c) pv = p[c];
            if (tid < NCls) op[t * NCls + tid] = pv * inv;
        }
        // No trailing barrier: phase A(t+1) writes zp (last read before B2) and
        // reads h0s (written before B2); phase E reads h1s, next written in
        // phase D(t+1) behind three barriers. All hazards fenced.
    }
}

extern "C" void kernel_launch(void* const* d_in, const int* in_sizes, int n_in,
                              void* d_out, int out_size, void* d_ws, size_t ws_size,
                              hipStream_t stream) {
    const float* inputs = (const float*)d_in[0];
    const float* times  = (const float*)d_in[1];
    const float* Wx0    = (const float*)d_in[2];
    const float* Wh0    = (const float*)d_in[3];
    const float* b0     = (const float*)d_in[4];
    const float* tau0   = (const float*)d_in[5];
    const float* s0     = (const float*)d_in[6];
    const float* Wx1    = (const float*)d_in[7];
    const float* Wh1    = (const float*)d_in[8];
    const float* b1     = (const float*)d_in[9];
    const float* tau1   = (const float*)d_in[10];
    const float* s1     = (const float*)d_in[11];
    const float* gamma_ = (const float*)d_in[12];
    const float* beta_  = (const float*)d_in[13];
    const float* Wfc    = (const float*)d_in[14];
    const float* bfc    = (const float*)d_in[15];
    float* out = (float*)d_out;

    dim3 grid(BATCH);
    dim3 block(1024);
    hipLaunchKernelGGL(plstm_fused, grid, block, 0, stream,
                       inputs, times, Wx0, Wh0, b0, tau0, s0,
                       Wx1, Wh1, b1, tau1, s1, gamma_, beta_, Wfc, bfc, out);
}

// Round 7
// 7087.228 us; speedup vs baseline: 2.4097x; 1.1215x over previous
//
#include <hip/hip_runtime.h>
#include <math.h>

// Problem constants (fixed by setup_inputs)
constexpr int U      = 128;   // UNITS
constexpr int G4     = 512;   // 4*U gate width
constexpr int NCls   = 10;    // classes
constexpr int TSTEPS = 1000;
constexpr int BATCH  = 256;
constexpr int CROWS  = 48;    // Wh0 rows cached in LDS (96 KB, rowgroups 0..2)

// ---------------------------------------------------------------------------
// Evidence ledger:
//  r0 naive per-use loads, 512 thr                     15.7 ms
//  r1-r3 cross-barrier register streaming              29-30 ms  (forbidden)
//  r4 per-use + 4 accs + LN-fold + 4 barriers           8.57 ms
//  r5 NB=4 batching (grid 64)                          17.1 ms  (idles CUs)
//  r6 1024 thr + partial-z + 128KB packed LDS cache     7.95 ms
// r6 model: port floor ~4.4 us/step but measured 8.6 -> issue-bound on
// scalar column loads (1 dword + 2 addr-VALU each). This version streams
// weights ROW-MAJOR as dwordx4: thread (g = tid>>7, c4 = tid&127) owns a
// row-slice x 4 consecutive cols -> load insts /4, addr ops /6, same bytes,
// perfect coalescing. 8 threads/column partial sums reduced via 16 KB LDS
// buffer zu (union: layer0 partials / layer1 partials). Gates do the 8-way
// add. Wh0 rows 0..47 cached in LDS row-major (96 KB) off the L1 port.
// LN fold (P/Q) unchanged; per-use loads only; 4 barriers/step.
// ---------------------------------------------------------------------------

__device__ __forceinline__ float sigm(float x) {
    return 1.0f / (1.0f + __expf(-x));
}

// k = time_gate(t, tau, s); floor-mod semantics matching jnp.mod
__device__ __forceinline__ float tgate(float t, float tau, float s) {
    float r = fmodf(t - s, tau);
    if (r < 0.0f) r += tau;
    const float phi = r / tau;
    return (phi < 0.025f) ? 40.0f * phi
         : (phi < 0.05f)  ? 2.0f - 40.0f * phi
         : 0.001f * phi;
}

// 4-row FMA block: ac.{x,y,z,w} are 4 output columns; hb broadcasts 4 rows.
#define ROW4(WP, I, HB) { \
    float4 w_; \
    w_ = (WP)[((I)+0)*128]; ac.x += (HB).x*w_.x; ac.y += (HB).x*w_.y; ac.z += (HB).x*w_.z; ac.w += (HB).x*w_.w; \
    w_ = (WP)[((I)+1)*128]; ac.x += (HB).y*w_.x; ac.y += (HB).y*w_.y; ac.z += (HB).y*w_.z; ac.w += (HB).y*w_.w; \
    w_ = (WP)[((I)+2)*128]; ac.x += (HB).z*w_.x; ac.y += (HB).z*w_.y; ac.z += (HB).z*w_.z; ac.w += (HB).z*w_.w; \
    w_ = (WP)[((I)+3)*128]; ac.x += (HB).w*w_.x; ac.y += (HB).w*w_.y; ac.z += (HB).w*w_.z; ac.w += (HB).w*w_.w; }

__global__ __launch_bounds__(1024, 1) void plstm_fused(
    const float* __restrict__ inputs,  // [B,T,3]
    const float* __restrict__ times,   // [B,T]
    const float* __restrict__ Wx0,     // [3,512]
    const float* __restrict__ Wh0,     // [128,512]
    const float* __restrict__ b0,      // [512]
    const float* __restrict__ tau0,    // [128]
    const float* __restrict__ s0,      // [128]
    const float* __restrict__ Wx1,     // [128,512]
    const float* __restrict__ Wh1,     // [128,512]
    const float* __restrict__ b1,      // [512]
    const float* __restrict__ tau1,    // [128]
    const float* __restrict__ s1,      // [128]
    const float* __restrict__ gamma_,  // [128]
    const float* __restrict__ beta_,   // [128]
    const float* __restrict__ Wfc,     // [128,10]
    const float* __restrict__ bfc,     // [10]
    float* __restrict__ out)           // [B,T,10]
{
    const int tid = threadIdx.x;        // 0..1023
    const int c4  = tid & 127;          // column quad (cols 4c4..4c4+3)
    const int g   = tid >> 7;           // rowgroup 0..7
    const int b   = blockIdx.x;

    __shared__ __align__(16) float wh0c[CROWS * G4];   // 96 KB (rows 0..47)
    __shared__ __align__(16) float zu[8 * G4];         // 16 KB partial-z union
    __shared__ __align__(16) float h0s[U];             // h0 state
    __shared__ __align__(16) float ghu[2 * U];         // [0..127]=gamma*h0, [128..255]=h1
    __shared__ __align__(16) float b0s[G4], b1s[G4], Ps[G4], Qs[G4];
    __shared__ __align__(16) float wx0s[3 * G4];
    __shared__ __align__(16) float wfcs[U * 11];       // stride 11
    __shared__ float bfcs[NCls];
    __shared__ float red[4];                           // {sum0,sq0,sum1,sq1}
    __shared__ float gms[U], bts[U];

    // ---- prologue: stage everything ----
    if (tid < U) { gms[tid] = gamma_[tid]; bts[tid] = beta_[tid];
                   h0s[tid] = 0.f; ghu[tid] = 0.f; ghu[U + tid] = 0.f; }
    {   // Wh0 rows 0..47 are the first 48*512 floats (contiguous): 6144 float4
        float4* dst = reinterpret_cast<float4*>(wh0c);
        const float4* src = reinterpret_cast<const float4*>(Wh0);
        #pragma unroll
        for (int i = 0; i < 6; ++i) dst[tid + i * 1024] = src[tid + i * 1024];
    }
    if (tid < G4) { b0s[tid] = b0[tid]; b1s[tid] = b1[tid]; }
    for (int i = tid; i < 3 * G4; i += 1024) wx0s[i] = Wx0[i];
    for (int i = tid; i < U * NCls; i += 1024) {
        const int u = i / NCls, c = i - u * NCls;
        wfcs[u * 11 + c] = Wfc[i];
    }
    if (tid < NCls) bfcs[tid] = bfc[tid];
    __syncthreads();

    // ---- LN fold constants per column: P[j]=sum beta[u]*Wx1[u][j],
    //      Q[j]=sum gamma[u]*Wx1[u][j] (threads 0..511, coalesced) ----
    if (tid < G4) {
        float P = 0.f, Q = 0.f;
        #pragma unroll 8
        for (int u = 0; u < U; ++u) {
            const float w = Wx1[u * G4 + tid];
            Q += gms[u] * w;
            P += bts[u] * w;
        }
        Ps[tid] = P; Qs[tid] = Q;
    }

    // ---- per-thread persistent parameters (gate threads only) ----
    float tau0r = 0.f, s0r = 0.f, tau1r = 0.f, s1r = 0.f, gr = 0.f;
    if (tid < U) {
        tau0r = tau0[tid]; s0r = s0[tid];
        tau1r = tau1[tid]; s1r = s1[tid];
        gr = gms[tid];
    }
    float c0r = 0.f, c1r = 0.f, h0r = 0.f, h1r = 0.f;

    const float* __restrict__ xp = inputs + (size_t)b * TSTEPS * 3;
    const float* __restrict__ tp = times  + (size_t)b * TSTEPS;
    float*       __restrict__ op = out    + (size_t)b * TSTEPS * NCls;

    float xa0 = xp[0], xa1 = xp[1], xa2 = xp[2], tva = tp[0];

    __syncthreads();

    for (int t = 0; t < TSTEPS; ++t) {
        const float x0 = xa0, x1 = xa1, x2 = xa2, tv = tva;
        const int tn = (t + 1 < TSTEPS) ? t + 1 : t;
        xa0 = xp[tn*3+0]; xa1 = xp[tn*3+1]; xa2 = xp[tn*3+2]; tva = tp[tn];

        // ---- phase A: matvec0 partials; rowgroup g (16 rows), cols 4c4.. ----
        {
            float4 ac = make_float4(0.f, 0.f, 0.f, 0.f);
            const int r0 = g * 16;
            if (g < 3) {   // cached rows from LDS (wave-uniform branch)
                const float4* wp = reinterpret_cast<const float4*>(wh0c) + r0 * 128 + c4;
                #pragma unroll 2
                for (int i = 0; i < 16; i += 4) {
                    const float4 hb = *reinterpret_cast<const float4*>(&h0s[r0 + i]);
                    ROW4(wp, i, hb);
                }
            } else {       // streamed rows, dwordx4 coalesced
                const float4* wp = reinterpret_cast<const float4*>(Wh0) + r0 * 128 + c4;
                #pragma unroll 2
                for (int i = 0; i < 16; i += 4) {
                    const float4 hb = *reinterpret_cast<const float4*>(&h0s[r0 + i]);
                    ROW4(wp, i, hb);
                }
            }
            *reinterpret_cast<float4*>(&zu[g * G4 + 4 * c4]) = ac;
        }
        __syncthreads();                                   // B1

        // ---- phase B: gates0 + LN partials (threads 0..127) ----
        if (tid < U) {
            const int u = tid;
            float z[4];
            #pragma unroll
            for (int q = 0; q < 4; ++q) {
                const int c = u + q * 128;
                float s = b0s[c] + x0 * wx0s[c] + x1 * wx0s[G4 + c] + x2 * wx0s[2 * G4 + c];
                #pragma unroll
                for (int gg = 0; gg < 8; ++gg) s += zu[gg * G4 + c];
                z[q] = s;
            }
            const float ig = sigm(z[0]);
            const float fg = sigm(z[1]);
            const float gg = tanhf(z[2]);
            const float og = sigm(z[3]);
            const float ch = fg * c0r + ig * gg;
            const float hh = og * tanhf(ch);
            const float k  = tgate(tv, tau0r, s0r);
            const float hn = k * hh + (1.0f - k) * h0r;
            c0r = k * ch + (1.0f - k) * c0r;
            h0r = hn;
            h0s[u] = hn;
            ghu[u] = gr * hn;
            float ssum = hn, qsum = hn * hn;               // one-pass variance
            #pragma unroll
            for (int off = 1; off < 64; off <<= 1) {
                ssum += __shfl_xor(ssum, off);
                qsum += __shfl_xor(qsum, off);
            }
            if ((tid & 63) == 0) {
                red[(tid >> 6) * 2]     = ssum;
                red[(tid >> 6) * 2 + 1] = qsum;
            }
        }
        __syncthreads();                                   // B2

        // ---- phase C: matvec1 partials (raw sums; LN applied in gates1) ----
        {
            // half 0 (tid<512): Wx1 x (gamma*h0) = ghu[0..127]
            // half 1          : Wh1 x h1        = ghu[128..255]
            const int half = tid >> 9;
            const int rg   = (tid >> 7) & 3;
            const int r0   = rg * 32;
            const float* __restrict__ Wm = half ? Wh1 : Wx1;
            const float* hvp = ghu + half * U + r0;        // LDS broadcast base
            const float4* wp = reinterpret_cast<const float4*>(Wm) + r0 * 128 + c4;
            float4 ac = make_float4(0.f, 0.f, 0.f, 0.f);
            #pragma unroll 2
            for (int i = 0; i < 32; i += 4) {
                const float4 hb = *reinterpret_cast<const float4*>(&hvp[i]);
                ROW4(wp, i, hb);
            }
            *reinterpret_cast<float4*>(&zu[(half * 4 + rg) * G4 + 4 * c4]) = ac;
        }
        __syncthreads();                                   // B3

        // ---- phase D: gates1 with LN fold (threads 0..127) ----
        if (tid < U) {
            const float mu    = (red[0] + red[2]) * (1.0f / 128.0f);
            const float msq   = (red[1] + red[3]) * (1.0f / 128.0f);
            const float rstd  = rsqrtf(msq - mu * mu + 1e-3f);
            const float murstd = mu * rstd;
            const int u = tid;
            float z[4];
            #pragma unroll
            for (int q = 0; q < 4; ++q) {
                const int c = u + q * 128;
                const float sx = (zu[0*G4+c] + zu[1*G4+c]) + (zu[2*G4+c] + zu[3*G4+c]);
                const float sh = (zu[4*G4+c] + zu[5*G4+c]) + (zu[6*G4+c] + zu[7*G4+c]);
                // z1 = b1 + P + rstd*Swx - mu*rstd*Q + Swh (exact LN fold)
                z[q] = b1s[c] + Ps[c] + rstd * sx - murstd * Qs[c] + sh;
            }
            const float ig = sigm(z[0]);
            const float fg = sigm(z[1]);
            const float gg = tanhf(z[2]);
            const float og = sigm(z[3]);
            const float ch = fg * c1r + ig * gg;
            const float hh = og * tanhf(ch);
            const float k  = tgate(tv, tau1r, s1r);
            const float hn = k * hh + (1.0f - k) * h1r;
            c1r = k * ch + (1.0f - k) * c1r;
            h1r = hn;
            ghu[U + u] = hn;                               // h1 state
        }
        __syncthreads();                                   // B4

        // ---- phase E: FC + softmax (wave 0); other waves roll into t+1 ----
        if (tid < 64) {
            const float a  = ghu[U + tid];
            const float bv = ghu[U + tid + 64];
            float p[NCls];
            #pragma unroll
            for (int c = 0; c < NCls; ++c)
                p[c] = a * wfcs[tid * 11 + c] + bv * wfcs[(tid + 64) * 11 + c];
            #pragma unroll
            for (int off = 1; off < 64; off <<= 1) {
                #pragma unroll
                for (int c = 0; c < NCls; ++c) p[c] += __shfl_xor(p[c], off);
            }
            float m = -1e30f;
            #pragma unroll
            for (int c = 0; c < NCls; ++c) { p[c] += bfcs[c]; m = fmaxf(m, p[c]); }
            float ssum = 0.0f;
            #pragma unroll
            for (int c = 0; c < NCls; ++c) { p[c] = __expf(p[c] - m); ssum += p[c]; }
            const float inv = 1.0f / ssum;
            float pv = p[0];               // static-index select (no scratch)
            #pragma unroll
            for (int c = 1; c < NCls; ++c) if (tid == c) pv = p[c];
            if (tid < NCls) op[t * NCls + tid] = pv * inv;
        }
        // No trailing barrier: phase A(t+1) writes zu (last read in D before
        // B4) and reads h0s (written in B before B2); phase E reads only
        // ghu[128..]/wfcs, rewritten next in D(t+1) behind 3 barriers.
    }
}

extern "C" void kernel_launch(void* const* d_in, const int* in_sizes, int n_in,
                              void* d_out, int out_size, void* d_ws, size_t ws_size,
                              hipStream_t stream) {
    const float* inputs = (const float*)d_in[0];
    const float* times  = (const float*)d_in[1];
    const float* Wx0    = (const float*)d_in[2];
    const float* Wh0    = (const float*)d_in[3];
    const float* b0     = (const float*)d_in[4];
    const float* tau0   = (const float*)d_in[5];
    const float* s0     = (const float*)d_in[6];
    const float* Wx1    = (const float*)d_in[7];
    const float* Wh1    = (const float*)d_in[8];
    const float* b1     = (const float*)d_in[9];
    const float* tau1   = (const float*)d_in[10];
    const float* s1     = (const float*)d_in[11];
    const float* gamma_ = (const float*)d_in[12];
    const float* beta_  = (const float*)d_in[13];
    const float* Wfc    = (const float*)d_in[14];
    const float* bfc    = (const float*)d_in[15];
    float* out = (float*)d_out;

    dim3 grid(BATCH);
    dim3 block(1024);
    hipLaunchKernelGGL(plstm_fused, grid, block, 0, stream,
                       inputs, times, Wx0, Wh0, b0, tau0, s0,
                       Wx1, Wh1, b1, tau1, s1, gamma_, beta_, Wfc, bfc, out);
}